// Round 13
// baseline (475.875 us; speedup 1.0000x reference)
//
#include <hip/hip_runtime.h>
#include <stdint.h>

// ---------------------------------------------------------------------------
// SchNetLayer on MI355X (gfx950).
// I/O: float tensors f32, indices int32. Internal: bf16 MFMA.
//
// R2: atomic scatter = atomic-rate bound -> counting sort.
// R3: libm softplus -> native v_exp/v_log.
// R4/R5: fuse gather/MLP/multiply/reduce into k_edge.
// R6-R8: LDS/occupancy tuning -> 128-edge tile, 3 blocks/CU, 159us.
// R9-R16: intra-tile k_edge redesigns (occupancy/atomics/barriers/LDS
//      round-trip) all lose to R8. R8 intra-tile structure = local optimum.
// R17: k_he/k_final HBM retile: NEUTRAL (z/he are L2/L3-resident).
// R18: single-phase tails + dispatch fusion: 401->392us (bubble ~3-4us/node).
// R19: T5 setprio around k_edge MFMA: k_edge 158.5->153.3us (+3%, real,
//      matches m191 role-diversity). Total flat (tail noise).
// R20: cross-tile pipelining — the one untried axis. Persistent k_edge
//      (768 blocks = 3/CU, 4 tiles each): intra-tile structure UNCHANGED;
//      next tile's pkt loads issue during GEMM1, its 8x float4 random-row
//      dist gathers issue after GEMM1 (in flight through SSP/GEMM2/reduce).
//      Hides the ~900cy HBM-gather latency exposed at every tile top.
//      +38 VGPR (118 < 170 cap for 3 waves/SIMD) — no spill.
// R21: resubmit of R20 — bench infra failed twice (no counters). Source
//      re-audited: no inter-block deps, uniform barriers, LDS commit
//      ordered by last bar of prior iter, bounds/VGPR ok. Infra flake
//      (same signature as R3; R12-era push times also show sick infra).
//
// Pipeline:
//   memset(cnt=0)
//   k_setup: z=0, weight transposes, edge histogram (one dispatch)
//   k_scan : per-type exclusive scan -> rowptr/cursor
//   k_place_he: blocks<1536 counting-sort place (packed u64 rec);
//               blocks>=1536 he = bf16(elec)@h_w (32x256 single-phase)
//   k_edge : persistent; per 128-edge tile: mid=SSP(dist[perm]@w1+b1);
//            per n0: we=mid@w2; per half: stage 64 src rows, weh=we*src,
//            16-row-strip segmented reduce -> fire-and-forget z atomics
//   k_final: out = elec + bf16(z)@gT^T (32x256 single-phase)
// ---------------------------------------------------------------------------

#define N_ELEC 8192
#define N_NUC  512
#define EMB    256
#define KER    256
#define DF     64
#define MID    128
#define NEDGE  131072
#define RPS    8256   // rowptr per-type stride (ints)
#define CSTR   272    // LDS row stride bytes for 128-col u16 tiles (+16 pad)
#define ASTR_HE 528   // he A-tile row stride bytes (256 bf16 + 8 pad)
#define ASTR_FN 1552  // k_final A-tile row stride bytes (768 bf16 + 8 pad)

using u16 = unsigned short;
using u64 = unsigned long long;
typedef short short8 __attribute__((ext_vector_type(8)));
typedef float f32x4 __attribute__((ext_vector_type(4)));

__device__ __forceinline__ float bf2f(u16 h) {
  return __uint_as_float(((unsigned)h) << 16);
}
__device__ __forceinline__ u16 f2bf(float f) {
  unsigned u = __float_as_uint(f);
  return (u16)((u + 0x7FFFu + ((u >> 16) & 1u)) >> 16);  // RNE
}
__device__ __forceinline__ unsigned pkbf(float a, float b) {
  return ((unsigned)f2bf(b) << 16) | (unsigned)f2bf(a);
}
// fast shifted softplus: log(0.5 e^x + 0.5), stable, native v_exp/v_log.
__device__ __forceinline__ float ssp_fast(float x) {
  const float e = __expf(-fabsf(x));
  return fmaxf(x, 0.f) + __logf(fmaf(0.5f, e, 0.5f));
}

// LDS-only workgroup barrier: no vmcnt drain; cross-wave deps in k_edge are
// LDS-only; z atomics + prefetch loads stay in flight. sched_barrier(0)
// both sides (rule #18) also pins prefetch issue points.
__device__ __forceinline__ void bar_lds() {
  __builtin_amdgcn_sched_barrier(0);
  asm volatile("s_waitcnt lgkmcnt(0)" ::: "memory");
  __builtin_amdgcn_s_barrier();
  __builtin_amdgcn_sched_barrier(0);
}

// ---- setup: z=0, weight transposes, histogram (single dispatch) ------------
__global__ __launch_bounds__(256) void k_setup(
    const float* h_w, const float* w1s, const float* w1a, const float* w1n,
    const float* w2s, const float* w2a, const float* w2n, const float* gs,
    const float* ga, const float* gn, const int* r0, const int* r1,
    const int* r2, u16* hwT, u16* w1T, u16* w2T, u16* gT, float4* z,
    int* cnt) {
  const int b = blockIdx.x;
  if (b < 6144) {
    z[b * 256 + threadIdx.x] = (float4){0.f, 0.f, 0.f, 0.f};
    return;
  }
  if (b >= 7648) {
    const int eb = b - 7648;
    const int t = eb >> 9;
    const int* rcv = t == 0 ? r0 : (t == 1 ? r1 : r2);
    const int e = ((eb & 511) << 8) + threadIdx.x;
    atomicAdd(&cnt[t * N_ELEC + rcv[e]], 1);
    return;
  }
  int i = (b - 6144) * 256 + threadIdx.x;
  if (i < 65536) {
    int n = i >> 8, k = i & 255;
    hwT[i] = f2bf(h_w[k * 256 + n]);
    return;
  }
  int j = i - 65536;
  if (j < 24576) {
    int t = j >> 13, jj = j & 8191, n = jj >> 6, k = jj & 63;
    const float* w1 = t == 0 ? w1s : (t == 1 ? w1a : w1n);
    w1T[j] = f2bf(w1[k * 128 + n]);
    return;
  }
  j -= 24576;
  if (j < 98304) {
    int t = j >> 15, jj = j & 32767, n = jj >> 7, k = jj & 127;
    const float* w2 = t == 0 ? w2s : (t == 1 ? w2a : w2n);
    w2T[j] = f2bf(w2[k * 256 + n]);
    return;
  }
  j -= 98304;
  if (j < 196608) {
    int n = j / 768, q = j % 768, t = q >> 8, k = q & 255;
    const float* g = t == 0 ? gs : (t == 1 ? ga : gn);
    gT[j] = f2bf(g[k * 256 + n]);
  }
}

__global__ __launch_bounds__(256) void k_scan(const int* cnt, int* rowptr,
                                              int* cursor) {
  const int t = blockIdx.x, tid = threadIdx.x;
  __shared__ int part[256];
  const int* c = cnt + t * N_ELEC;
  int s = 0;
#pragma unroll
  for (int i = 0; i < 32; ++i) s += c[tid * 32 + i];
  part[tid] = s;
  __syncthreads();
  for (int off = 1; off < 256; off <<= 1) {
    int v = (tid >= off) ? part[tid - off] : 0;
    __syncthreads();
    part[tid] += v;
    __syncthreads();
  }
  int run = (tid == 0) ? 0 : part[tid - 1];
  int* rp = rowptr + t * RPS;
  int* cu = cursor + t * N_ELEC;
  for (int i = 0; i < 32; ++i) {
    rp[tid * 32 + i] = run;
    cu[tid * 32 + i] = run;
    run += c[tid * 32 + i];
  }
  if (tid == 255) rp[N_ELEC] = run;  // = NEDGE
}

// ---- fused place + he dispatch ---------------------------------------------
__global__ __launch_bounds__(256) void k_place_he(
    const int* r0, const int* r1, const int* r2, const int* s0, const int* s1,
    const int* s2, int* cursor, u64* pk, const float* elec, const u16* hwT,
    u16* he) {
  __shared__ __align__(16) char As[32 * ASTR_HE];  // 16896 B (he path only)
  const int bid = blockIdx.x, tid = threadIdx.x;
  if (bid < 1536) {
    const int t = bid >> 9;
    const int* rcv = t == 0 ? r0 : (t == 1 ? r1 : r2);
    const int* snd = t == 0 ? s0 : (t == 1 ? s1 : s2);
    const int e = ((bid & 511) << 8) + tid;
    const int rr = rcv[e];
    const int pos = atomicAdd(&cursor[t * N_ELEC + rr], 1);
    pk[t * NEDGE + pos] = (u64)(unsigned)e | ((u64)(unsigned)snd[e] << 17) |
                          ((u64)(unsigned)rr << 30);
    return;
  }
  const int m0 = (bid - 1536) * 32;
#pragma unroll
  for (int i = 0; i < 16; ++i) {
    const int idx = i * 256 + tid;
    const int row = idx >> 7, cp = idx & 127;
    const float2 v = *(const float2*)(elec + (long)(m0 + row) * 256 + cp * 2);
    *(unsigned*)(As + row * ASTR_HE + cp * 4) = pkbf(v.x, v.y);
  }
  __syncthreads();
  const int l = tid & 63, lane15 = l & 15, quad = l >> 4, wv = tid >> 6;
  const int nw = wv * 64;
  f32x4 acc[2][4];
#pragma unroll
  for (int i = 0; i < 2; ++i)
#pragma unroll
    for (int j = 0; j < 4; ++j) acc[i][j] = (f32x4){0.f, 0.f, 0.f, 0.f};
  for (int kt = 0; kt < 256; kt += 32) {
    short8 af[2], bf[4];
#pragma unroll
    for (int i = 0; i < 2; ++i)
      af[i] = *(const short8*)(As + (i * 16 + lane15) * ASTR_HE + kt * 2 +
                               quad * 16);
#pragma unroll
    for (int i = 0; i < 4; ++i)
      bf[i] = *(const short8*)(hwT + (nw + i * 16 + lane15) * 256 + kt +
                               quad * 8);
#pragma unroll
    for (int mi = 0; mi < 2; ++mi)
#pragma unroll
      for (int ni = 0; ni < 4; ++ni)
        acc[mi][ni] = __builtin_amdgcn_mfma_f32_16x16x32_bf16(
            af[mi], bf[ni], acc[mi][ni], 0, 0, 0);
  }
#pragma unroll
  for (int mi = 0; mi < 2; ++mi)
#pragma unroll
    for (int r = 0; r < 4; ++r) {
      const int row = m0 + mi * 16 + quad * 4 + r;
#pragma unroll
      for (int ni = 0; ni < 4; ++ni) {
        const int col = nw + ni * 16 + lane15;
        he[row * 256 + col] = f2bf(acc[mi][ni][r]);
      }
    }
}

// ---- persistent fused edge kernel (R20) ------------------------------------
// 768 blocks (3/CU), 4 tiles each. Intra-tile = frozen R8+setprio structure.
// Cross-tile prefetch: next pkt during GEMM1; next dist gathers after GEMM1
// (in flight through SSP/GEMM2/halves); committed to LDS at next tile top.
__global__ __launch_bounds__(256, 3) void k_edge(
    const float* d0, const float* d1, const float* d2, const float* b0,
    const float* b1p, const float* b2, const u16* w1T, const u16* w2T,
    const u16* he, const float* nucf, const u64* pk, float* z) {
  __shared__ char mid[128 * CSTR];  // 34816 B: dist halves -> mid
  __shared__ char hc[64 * CSTR];    // 17408 B: per-half He/weh tile
  __shared__ int snd_l[128], rcv_l[128];

  const int t = blockIdx.z;
  const int tid = threadIdx.x;
  const float* dist = t == 0 ? d0 : (t == 1 ? d1 : d2);
  const float* bias = t == 0 ? b0 : (t == 1 ? b1p : b2);
  const u16* w1t = w1T + t * 8192;   // [128][64]
  const u16* w2t = w2T + t * 32768;  // [256][128]
  const bool is_nuc = (t == 2);
  const u64* pkbase = pk + (size_t)t * NEDGE;

  const int l = tid & 63, lane15 = l & 15, quad = l >> 4, wv = tid >> 6;
  const int mw = (wv >> 1) * 64, nw = (wv & 1) * 64;

  // ---- prefetch tile 0 (blockIdx.x) ----
  int tile = blockIdx.x;  // 0..255; tile id = tile + it*256
  u64 rec_pf = 0;
  int rows_pf[4];
  float4 dv[2][4];
  {
    const u64* pkt = pkbase + (size_t)tile * 128;
    if (tid < 128) rec_pf = pkt[tid];
#pragma unroll
    for (int s = 0; s < 4; ++s)
      rows_pf[s] = (int)(pkt[(s * 256 + tid) >> 3] & 0x1FFFFu);
#pragma unroll
    for (int j = 0; j < 2; ++j)
#pragma unroll
      for (int s = 0; s < 4; ++s) {
        const int ch = (s * 256 + tid) & 7;
        dv[j][s] =
            *(const float4*)(dist + (long)rows_pf[s] * 64 + j * 32 + ch * 4);
      }
  }

  for (int it = 0; it < 4; ++it) {
    // ---- commit prefetched tile into LDS (prev iter's last bar covers) ----
    if (tid < 128) {
      snd_l[tid] = (int)((rec_pf >> 17) & 0x1FFFu);
      rcv_l[tid] = (int)(rec_pf >> 30);
    }
#pragma unroll
    for (int j = 0; j < 2; ++j)
#pragma unroll
      for (int s = 0; s < 4; ++s) {
        const int idx = s * 256 + tid, row = idx >> 3, ch = idx & 7;
        uint2 p;
        p.x = pkbf(dv[j][s].x, dv[j][s].y);
        p.y = pkbf(dv[j][s].z, dv[j][s].w);
        *(uint2*)(mid + j * 8192 + row * 64 + ch * 8) = p;
      }
    bar_lds();

    // ---- issue next tile's pkt loads (in flight during GEMM1) ----
    u64 rec_n = 0;
    int rows_n[4];
    const int ntile = tile + 256;
    if (it < 3) {
      const u64* pn = pkbase + (size_t)ntile * 128;
      if (tid < 128) rec_n = pn[tid];
#pragma unroll
      for (int s = 0; s < 4; ++s)
        rows_n[s] = (int)(pn[(s * 256 + tid) >> 3] & 0x1FFFFu);
    }

    // GEMM1: [128,64] @ [64,128] -> acc  (B = w1t global, L2-hot)
    f32x4 acc[4][4];
#pragma unroll
    for (int i = 0; i < 4; ++i)
#pragma unroll
      for (int j = 0; j < 4; ++j) acc[i][j] = (f32x4){0.f, 0.f, 0.f, 0.f};
#pragma unroll
    for (int j = 0; j < 2; ++j) {
      short8 af[4], bf[4];
#pragma unroll
      for (int i = 0; i < 4; ++i) {
        af[i] = *(const short8*)(mid + j * 8192 + (mw + i * 16 + lane15) * 64 +
                                 quad * 16);
        bf[i] = *(const short8*)(w1t + (nw + i * 16 + lane15) * 64 + j * 32 +
                                 quad * 8);
      }
      __builtin_amdgcn_s_setprio(1);
#pragma unroll
      for (int mi = 0; mi < 4; ++mi)
#pragma unroll
        for (int ni = 0; ni < 4; ++ni)
          acc[mi][ni] = __builtin_amdgcn_mfma_f32_16x16x32_bf16(
              af[mi], bf[ni], acc[mi][ni], 0, 0, 0);
      __builtin_amdgcn_s_setprio(0);
    }
    bar_lds();  // all waves done reading dist halves

    // ---- issue next tile's dist gathers (in flight thru SSP/GEMM2/halves) -
    if (it < 3) {
#pragma unroll
      for (int j = 0; j < 2; ++j)
#pragma unroll
        for (int s = 0; s < 4; ++s) {
          const int ch = (s * 256 + tid) & 7;
          dv[j][s] =
              *(const float4*)(dist + (long)rows_n[s] * 64 + j * 32 + ch * 4);
        }
    }

    // bias + SSP -> mid (272 B rows)
#pragma unroll
    for (int mi = 0; mi < 4; ++mi)
#pragma unroll
      for (int r = 0; r < 4; ++r) {
        const int row = mw + mi * 16 + quad * 4 + r;
#pragma unroll
        for (int ni = 0; ni < 4; ++ni) {
          const int col = nw + ni * 16 + lane15;
          const float x = acc[mi][ni][r] + bias[col];
          *(u16*)(mid + row * CSTR + col * 2) = f2bf(ssp_fast(x));
        }
      }
    bar_lds();  // mid visible to all waves

    for (int n0 = 0; n0 < 256; n0 += 128) {
      // GEMM2: A = mid (LDS), B = w2t cols n0.. (global, L2-hot)
#pragma unroll
      for (int i = 0; i < 4; ++i)
#pragma unroll
        for (int j = 0; j < 4; ++j) acc[i][j] = (f32x4){0.f, 0.f, 0.f, 0.f};
#pragma unroll
      for (int kt = 0; kt < 128; kt += 32) {
        short8 af[4], bf[4];
#pragma unroll
        for (int i = 0; i < 4; ++i) {
          af[i] = *(const short8*)(mid + (mw + i * 16 + lane15) * CSTR +
                                   kt * 2 + quad * 16);
          bf[i] = *(const short8*)(w2t + (n0 + nw + i * 16 + lane15) * 128 +
                                   kt + quad * 8);
        }
        __builtin_amdgcn_s_setprio(1);
#pragma unroll
        for (int mi = 0; mi < 4; ++mi)
#pragma unroll
          for (int ni = 0; ni < 4; ++ni)
            acc[mi][ni] = __builtin_amdgcn_mfma_f32_16x16x32_bf16(
                af[mi], bf[ni], acc[mi][ni], 0, 0, 0);
        __builtin_amdgcn_s_setprio(0);
      }

      for (int h = 0; h < 2; ++h) {
        const int rbase = h * 64;
        // stage 64 src rows (cols n0..n0+128) into hc (16 B chunks)
        if (!is_nuc) {
#pragma unroll
          for (int c = 0; c < 4; ++c) {
            const int chunk = c * 256 + tid;  // 1024 x 16 B
            const int row = chunk >> 4, off = chunk & 15;
            const uint4 v =
                *(const uint4*)((const char*)he +
                                (size_t)snd_l[rbase + row] * 512 + n0 * 2 +
                                off * 16);
            *(uint4*)(hc + row * CSTR + off * 16) = v;
          }
        } else {
#pragma unroll
          for (int c = 0; c < 4; ++c) {
            const int chunk = c * 256 + tid;
            const int row = chunk >> 4, off = chunk & 15;
            const char* src = (const char*)nucf +
                              (size_t)snd_l[rbase + row] * 1024 + n0 * 4 +
                              off * 32;
            const float4 a = *(const float4*)src;
            const float4 b = *(const float4*)(src + 16);
            uint4 p;
            p.x = pkbf(a.x, a.y);
            p.y = pkbf(a.z, a.w);
            p.z = pkbf(b.x, b.y);
            p.w = pkbf(b.z, b.w);
            *(uint4*)(hc + row * CSTR + off * 16) = p;
          }
        }
        bar_lds();

        // in-place multiply: waves whose fragment rows live in this half
        if ((wv >> 1) == h) {
#pragma unroll
          for (int mi = 0; mi < 4; ++mi)
#pragma unroll
            for (int r = 0; r < 4; ++r) {
              const int lrow = mi * 16 + quad * 4 + r;  // 0..63 in half
#pragma unroll
              for (int ni = 0; ni < 4; ++ni) {
                const int col = nw + ni * 16 + lane15;
                u16* p = (u16*)(hc + lrow * CSTR) + col;
                *p = f2bf(acc[mi][ni][r] * bf2f(*p));
              }
            }
        }
        bar_lds();

        // segmented reduce: wave wv owns 16 rows; lane owns a col pair.
        // Fire-and-forget atomics (bar_lds never drains vmcnt).
        {
          const int cp = l;
          const int rbeg = wv * 16, rend = rbeg + 16;
          float a0 = 0.f, a1 = 0.f;
          int cur = rcv_l[rbase + rbeg];
          for (int row = rbeg; row < rend; ++row) {
            const unsigned p = *(const unsigned*)(hc + row * CSTR + cp * 4);
            a0 += __uint_as_float(p << 16);
            a1 += __uint_as_float(p & 0xffff0000u);
            const int nxt = (row + 1 < rend) ? rcv_l[rbase + row + 1] : -1;
            if (nxt != cur) {
              float* zp = z + (size_t)cur * 768 + t * 256 + n0 + cp * 2;
              unsafeAtomicAdd(zp, a0);
              unsafeAtomicAdd(zp + 1, a1);
              a0 = a1 = 0.f;
              cur = nxt;
            }
          }
        }
        bar_lds();  // hc reused next half / n0; also guards mid/meta commit
      }
    }
    rec_pf = rec_n;
    tile = ntile;
  }
}

// ---- out = elec + bf16(z) @ gT^T  (32x256 tiles, single-phase) -------------
__global__ __launch_bounds__(256) void k_final(const float* z, const u16* gT,
                                               const float* elec, float* out) {
  __shared__ __align__(16) char As[32 * ASTR_FN];  // 49664 B
  const int tid = threadIdx.x;
  const int m0 = blockIdx.x * 32;
#pragma unroll
  for (int i = 0; i < 24; ++i) {
    const int idx = i * 256 + tid;  // 0..6143
    const int row = idx / 192, q = idx % 192;
    const float4 v = *(const float4*)(z + (long)(m0 + row) * 768 + q * 4);
    uint2 p;
    p.x = pkbf(v.x, v.y);
    p.y = pkbf(v.z, v.w);
    *(uint2*)(As + row * ASTR_FN + q * 8) = p;
  }
  __syncthreads();
  const int l = tid & 63, lane15 = l & 15, quad = l >> 4, wv = tid >> 6;
  const int nw = wv * 64;
  f32x4 acc[2][4];
#pragma unroll
  for (int i = 0; i < 2; ++i)
#pragma unroll
    for (int j = 0; j < 4; ++j) acc[i][j] = (f32x4){0.f, 0.f, 0.f, 0.f};
  for (int kt = 0; kt < 768; kt += 32) {
    short8 af[2], bf[4];
#pragma unroll
    for (int i = 0; i < 2; ++i)
      af[i] = *(const short8*)(As + (i * 16 + lane15) * ASTR_FN + kt * 2 +
                               quad * 16);
#pragma unroll
    for (int i = 0; i < 4; ++i)
      bf[i] = *(const short8*)(gT + (nw + i * 16 + lane15) * 768 + kt +
                               quad * 8);
#pragma unroll
    for (int mi = 0; mi < 2; ++mi)
#pragma unroll
      for (int ni = 0; ni < 4; ++ni)
        acc[mi][ni] = __builtin_amdgcn_mfma_f32_16x16x32_bf16(
            af[mi], bf[ni], acc[mi][ni], 0, 0, 0);
  }
#pragma unroll
  for (int mi = 0; mi < 2; ++mi)
#pragma unroll
    for (int r = 0; r < 4; ++r) {
      const int row = m0 + mi * 16 + quad * 4 + r;
#pragma unroll
      for (int ni = 0; ni < 4; ++ni) {
        const int col = nw + ni * 16 + lane15;
        out[row * 256 + col] = acc[mi][ni][r] + elec[row * 256 + col];
      }
    }
}

// ---------------------------------------------------------------------------
extern "C" void kernel_launch(void* const* d_in, const int* in_sizes, int n_in,
                              void* d_out, int out_size, void* d_ws,
                              size_t ws_size, hipStream_t stream) {
  int I_dist[3], I_w1[3], I_b1[3], I_w2[3], I_g[3], I_hw;
  if (in_sizes[3] == 64 * 128) {  // setup_inputs() dict order
    for (int t = 0; t < 3; ++t) {
      I_dist[t] = 2 + t * 5 + 0;
      I_w1[t] = 2 + t * 5 + 1;
      I_b1[t] = 2 + t * 5 + 2;
      I_w2[t] = 2 + t * 5 + 3;
      I_g[t] = 2 + t * 5 + 4;
    }
    I_hw = 17;
  } else {  // reference signature order
    I_dist[0] = 2; I_dist[1] = 3; I_dist[2] = 4;
    I_w1[0] = 5;  I_b1[0] = 6;  I_w2[0] = 7;
    I_w1[1] = 8;  I_b1[1] = 9;  I_w2[1] = 10;
    I_w1[2] = 11; I_b1[2] = 12; I_w2[2] = 13;
    I_g[0] = 14; I_g[1] = 15; I_g[2] = 16;
    I_hw = 17;
  }
  const int I_snd[3] = {18, 19, 20};
  const int I_rcv[3] = {21, 22, 23};

  char* ws = (char*)d_ws;
  // workspace layout (bytes). Total ~34 MB.
  u16* he = (u16*)(ws + 0);              //   4,194,304
  u16* hwT = (u16*)(ws + 4194304);       //     131,072
  u16* w1T = (u16*)(ws + 4325376);       //      49,152
  u16* w2T = (u16*)(ws + 4374528);       //     196,608
  u16* gT = (u16*)(ws + 4571136);        //     393,216
  float* z = (float*)(ws + 4964352);     //  25,165,824
  int* cnt = (int*)(ws + 30130176);      //      98,304
  int* rowptr = (int*)(ws + 30228480);   //      99,072
  int* cursor = (int*)(ws + 30327552);   //      98,304
  u64* pk = (u64*)(ws + 30425856);       //   3,145,728

  const float* elec = (const float*)d_in[0];
  const float* nuc = (const float*)d_in[1];
  const int* s0 = (const int*)d_in[I_snd[0]];
  const int* s1 = (const int*)d_in[I_snd[1]];
  const int* s2 = (const int*)d_in[I_snd[2]];
  const int* r0 = (const int*)d_in[I_rcv[0]];
  const int* r1 = (const int*)d_in[I_rcv[1]];
  const int* r2 = (const int*)d_in[I_rcv[2]];

  // cnt = 0 (memset node; k_setup's histogram blocks atomically build on it)
  hipMemsetAsync(cnt, 0, 98304, stream);

  // z=0 (6144) + transposes (1504) + histogram (1536) in one dispatch
  k_setup<<<9184, 256, 0, stream>>>(
      (const float*)d_in[I_hw], (const float*)d_in[I_w1[0]],
      (const float*)d_in[I_w1[1]], (const float*)d_in[I_w1[2]],
      (const float*)d_in[I_w2[0]], (const float*)d_in[I_w2[1]],
      (const float*)d_in[I_w2[2]], (const float*)d_in[I_g[0]],
      (const float*)d_in[I_g[1]], (const float*)d_in[I_g[2]], r0, r1, r2,
      hwT, w1T, w2T, gT, (float4*)z, cnt);

  k_scan<<<3, 256, 0, stream>>>(cnt, rowptr, cursor);

  // place (1536 blocks) + he (256 blocks) in one dispatch
  k_place_he<<<1792, 256, 0, stream>>>(r0, r1, r2, s0, s1, s2, cursor, pk,
                                       elec, hwT, he);

  // persistent: 256 x-blocks x 3 types = 768 blocks (3/CU), 4 tiles each
  k_edge<<<dim3(256, 1, 3), 256, 0, stream>>>(
      (const float*)d_in[I_dist[0]], (const float*)d_in[I_dist[1]],
      (const float*)d_in[I_dist[2]], (const float*)d_in[I_b1[0]],
      (const float*)d_in[I_b1[1]], (const float*)d_in[I_b1[2]], w1T, w2T, he,
      nuc, pk, z);

  k_final<<<N_ELEC / 32, 256, 0, stream>>>(z, gT, elec, (float*)d_out);
}